// Round 12
// baseline (210.594 us; speedup 1.0000x reference)
//
#include <hip/hip_runtime.h>
#include <hip/hip_bf16.h>

#define LATENT 4096
#define SDIM   64
#define MT     5              // 5 m-tiles of 16 = 80 rows (64 outputs + s_row + pad)
#define CHUNK  128            // floats of K per staged chunk (= 4 k-steps)
#define NCHK   (LATENT / CHUNK)   // 32
#define NBUF   4
#define ROWS   32             // batch rows per block
#define WS_NEED (4096 + 40960 * 16)

typedef __bf16 bf16x8 __attribute__((ext_vector_type(8)));
typedef float  f32x4  __attribute__((ext_vector_type(4)));

#define GLOBAL_AS __attribute__((address_space(1)))
#define LDS_AS    __attribute__((address_space(3)))

__device__ __forceinline__ void load_lds16(const float* g, float* l) {
    __builtin_amdgcn_global_load_lds((const GLOBAL_AS void*)g, (LDS_AS void*)l, 16, 0, 0);
}

#define WAITB(N) do { asm volatile("s_waitcnt vmcnt(" #N ")" ::: "memory"); \
                      __builtin_amdgcn_s_barrier(); } while (0)

// ======================= precompute path (needs d_ws) =======================
// Merged prep: blocks 0..159 build afrag; block 160 builds c[].
__global__ __launch_bounds__(256) void prep_all(
    const float* __restrict__ wq, const float* __restrict__ wk,
    const float* __restrict__ Wf, const int* __restrict__ midx,
    const float* __restrict__ bq, const float* __restrict__ bk,
    int F, bf16x8* __restrict__ afrag, float* __restrict__ c)
{
    const int t = threadIdx.x;
    if (blockIdx.x == 160) {
        const int o = t >> 2, sub = t & 3;
        float p = 0.f;
        for (int f = sub; f < F; f += 4) p += bk[f] * Wf[o * F + f];
        p += __shfl_xor(p, 1); p += __shfl_xor(p, 2);
        if (sub == 0) c[o] = p;
        if (t < 64) {
            float q = 0.f;
            for (int f = t; f < F; f += 64) q += bq[f];
            #pragma unroll
            for (int off = 32; off; off >>= 1) q += __shfl_down(q, off);
            if (t == 0) c[SDIM] = q;
        }
        return;
    }

    __shared__ int inv[LATENT];
    #pragma unroll
    for (int d = t; d < LATENT; d += 256) inv[d] = -1;
    __syncthreads();
    for (int f = t; f < F; f += 256) inv[midx[f]] = f;
    __syncthreads();

    const int g = blockIdx.x * 256 + t;          // 0 .. 40959
    const int lane = g & 63;
    const int mt = (g >> 6) % 5;
    const int ks = g / 320;                      // 0 .. 127
    const int m = mt * 16 + (lane & 15);
    const int kbase = ks * 32 + (lane >> 4) * 8;
    bf16x8 v;
    #pragma unroll
    for (int j = 0; j < 8; ++j) {
        int f = inv[kbase + j];
        float x = 0.f;
        if (f >= 0) {
            if (m < SDIM) x = wk[f] * Wf[m * F + f];
            else if (m == SDIM) x = wq[f];
        }
        v[j] = (__bf16)x;
    }
    afrag[g] = v;
}

struct AF { bf16x8 a0, a1, a2, a3, a4; };

// main: D[80 x 16384] = A[80 x 4096] * z^T, counted-vmcnt deep ring pipeline.
// 512 blocks x 512 thr (8 waves): wave = (kq 0..3) x (nh 0..1), ng=1 each.
// 2 blocks/CU (64KB LDS) x 8 waves = 16 waves/CU = 4/SIMD — 2x r10 occupancy
// with per-wave VGPR ~115 (spill-safe under launch_bounds(512,3) cap of 170).
__global__ __launch_bounds__(512, 3) void gemm_pipe(
    const float* __restrict__ z, const bf16x8* __restrict__ afrag,
    const float* __restrict__ c, const float* __restrict__ bfin,
    float* __restrict__ out)
{
    __shared__ __align__(16) float zbuf[NBUF][ROWS][CHUNK];   // 64 KB
    float (*red)[2][MT][4][64] = (float (*)[2][MT][4][64])zbuf;  // [grp][nh][mt][r][lane]

    const int tid  = threadIdx.x;
    const int lane = tid & 63;
    const int wid  = tid >> 6;     // 0..7
    const int kq   = wid & 3;      // k-step within chunk
    const int nh   = wid >> 2;     // n-half (rows 0-15 / 16-31)
    const int col  = lane & 15;
    const int g4   = lane >> 4;
    const int r0   = blockIdx.x * ROWS;
    const int ra   = 4 * wid;      // this wave stages LDS rows ra..ra+3

    // global sources for the 2 staging instrs; column pre-swizzled so that
    // LDS float pos p (linear dest) holds z col (p ^ ((ldsrow&7)<<2)).
    const int half  = lane >> 5;          // 0..1 (row within a 2-row pair)
    const int cbase = (lane & 31) * 4;    // 16B slot within row
    const int lr0 = ra + half, lr1 = ra + 2 + half;
    const float* zsrc0 = z + (size_t)(r0 + lr0) * LATENT + (cbase ^ ((lr0 & 7) << 2));
    const float* zsrc1 = z + (size_t)(r0 + lr1) * LATENT + (cbase ^ ((lr1 & 7) << 2));

    f32x4 acc[MT] = {};

    auto stage = [&](int cN) {   // 2 VMEM ops (4 LDS rows)
        float* d = &zbuf[cN & 3][ra][0];
        load_lds16(zsrc0 + cN * CHUNK, d);
        load_lds16(zsrc1 + cN * CHUNK, d + 256);
    };
    auto loadA = [&](int cN, AF& Fr) {   // 5 VMEM ops
        const bf16x8* p = afrag + (size_t)((cN * 4 + kq) * MT) * 64 + lane;
        Fr.a0 = p[0]; Fr.a1 = p[64]; Fr.a2 = p[128]; Fr.a3 = p[192]; Fr.a4 = p[256];
    };
    auto consume = [&](int cN, const AF& Fr) {
        const int q = cN & 3;
        const int base = kq * 32 + g4 * 8;         // multiple of 8
        const int b0 = base ^ ((col & 7) << 2);    // 16B-aligned
        const float* pr = &zbuf[q][nh * 16 + col][0];
        f32x4 a = *(const f32x4*)(pr + b0);
        f32x4 b = *(const f32x4*)(pr + (b0 ^ 4));
        bf16x8 bv;
        bv[0] = (__bf16)a[0]; bv[1] = (__bf16)a[1];
        bv[2] = (__bf16)a[2]; bv[3] = (__bf16)a[3];
        bv[4] = (__bf16)b[0]; bv[5] = (__bf16)b[1];
        bv[6] = (__bf16)b[2]; bv[7] = (__bf16)b[3];
        acc[0] = __builtin_amdgcn_mfma_f32_16x16x32_bf16(Fr.a0, bv, acc[0], 0, 0, 0);
        acc[1] = __builtin_amdgcn_mfma_f32_16x16x32_bf16(Fr.a1, bv, acc[1], 0, 0, 0);
        acc[2] = __builtin_amdgcn_mfma_f32_16x16x32_bf16(Fr.a2, bv, acc[2], 0, 0, 0);
        acc[3] = __builtin_amdgcn_mfma_f32_16x16x32_bf16(Fr.a3, bv, acc[3], 0, 0, 0);
        acc[4] = __builtin_amdgcn_mfma_f32_16x16x32_bf16(Fr.a4, bv, acc[4], 0, 0, 0);
    };

    AF f_a, f_b, f_c;
    // prologue: sets 0,1 in flight (7 ops each -> 14 outstanding)
    loadA(0, f_a); stage(0);
    loadA(1, f_b); stage(1);

    // steady state: issue set h+2, WAIT vmcnt(14) (leaves {h+1,h+2}), consume h.
    for (int hb = 0; hb < NCHK - 2; hb += 3) {
        loadA(hb + 2, f_c); stage(hb + 2);
        WAITB(14); consume(hb,     f_a);
        loadA(hb + 3, f_a); stage(hb + 3);
        WAITB(14); consume(hb + 1, f_b);
        loadA(hb + 4, f_b); stage(hb + 4);
        WAITB(14); consume(hb + 2, f_c);
    }
    // tail: outstanding = sets {30,31}
    WAITB(7); consume(30, f_a);
    WAITB(0); consume(31, f_b);

    // ---- reduce the 4 kq partials per n-half (zbuf reused; barrier protects) ----
    __syncthreads();
    if (kq >= 2) {
        #pragma unroll
        for (int mt = 0; mt < MT; ++mt)
            #pragma unroll
            for (int r = 0; r < 4; ++r) red[kq - 2][nh][mt][r][lane] = acc[mt][r];
    }
    __syncthreads();
    if (kq < 2) {
        #pragma unroll
        for (int mt = 0; mt < MT; ++mt)
            #pragma unroll
            for (int r = 0; r < 4; ++r) acc[mt][r] += red[kq][nh][mt][r][lane];
    }
    __syncthreads();
    if (kq == 1) {
        #pragma unroll
        for (int mt = 0; mt < MT; ++mt)
            #pragma unroll
            for (int r = 0; r < 4; ++r) red[2][nh][mt][r][lane] = acc[mt][r];
    }
    __syncthreads();
    if (kq == 0) {
        #pragma unroll
        for (int mt = 0; mt < MT; ++mt)
            #pragma unroll
            for (int r = 0; r < 4; ++r) acc[mt][r] += red[2][nh][mt][r][lane];

        // s-row (m=64) lives in acc[4][0] of lanes 0-15; broadcast via shuffle
        const float s = __shfl(acc[4][0], col) + c[SDIM];
        const int b = r0 + nh * 16 + col;
        #pragma unroll
        for (int mt = 0; mt < 4; ++mt) {
            f32x4 cv = *(const f32x4*)(c    + mt * 16 + g4 * 4);
            f32x4 bf = *(const f32x4*)(bfin + mt * 16 + g4 * 4);
            f32x4 ov;
            #pragma unroll
            for (int r = 0; r < 4; ++r) ov[r] = s * (acc[mt][r] + cv[r]) + bf[r];
            *(f32x4*)(out + (size_t)b * SDIM + mt * 16 + g4 * 4) = ov;
        }
    }
}

// ================== fused fallback (round-2 kernel, verbatim) ==================
#define BK     128
#define NCH    (LATENT / BK)

__global__ __launch_bounds__(512, 2) void fused_kernel(
    const float* __restrict__ z,
    const float* __restrict__ wq, const float* __restrict__ bq,
    const float* __restrict__ wk, const float* __restrict__ bk,
    const float* __restrict__ Wf, const float* __restrict__ bfin,
    const int* __restrict__ midx, int F,
    float* __restrict__ out)
{
    __shared__ __align__(16) unsigned char ubuf[2 * 80 * BK * 2];
    __shared__ int   inv[LATENT];
    __shared__ float cvals[68];
    __shared__ float srow[4][16];

    __bf16* Ab = (__bf16*)ubuf;
    float (*red)[MT][4][64] = (float (*)[MT][4][64])ubuf;

    const int tid  = threadIdx.x;
    const int lane = tid & 63;
    const int w    = tid >> 6;
    const int rg   = w & 3;
    const int kh   = w >> 2;
    const int r0   = blockIdx.x * 64 + rg * 16;
    const int col  = lane & 15;
    const int g4   = lane >> 4;

    for (int d = tid; d < LATENT; d += 512) inv[d] = -1;
    __syncthreads();
    for (int f = tid; f < F; f += 512) inv[midx[f]] = f;
    {
        const int o = tid >> 3, fo = tid & 7;
        float p = 0.f;
        for (int f = fo; f < F; f += 8) p += bk[f] * Wf[o * F + f];
        p += __shfl_xor(p, 1); p += __shfl_xor(p, 2); p += __shfl_xor(p, 4);
        if (fo == 0) cvals[o] = p;
    }
    if (w == 0) {
        float q = 0.f;
        for (int f = lane; f < F; f += 64) q += bq[f];
        #pragma unroll
        for (int off = 32; off; off >>= 1) q += __shfl_down(q, off);
        if (lane == 0) cvals[64] = q;
    }
    __syncthreads();

    f32x4 acc[MT] = {};

    auto build = [&](int ch, int b) {
        const int k  = tid & 127;
        const int mb = tid >> 7;
        const int f  = inv[ch * BK + k];
        const float wkf = (f >= 0) ? wk[f] : 0.f;
        const float wqf = (f >= 0) ? wq[f] : 0.f;
        __bf16* dst = Ab + b * 80 * BK;
        #pragma unroll
        for (int i = 0; i < 20; ++i) {
            const int m = mb + 4 * i;
            float x = 0.f;
            if (m < SDIM) { if (f >= 0) x = wkf * Wf[m * F + f]; }
            else if (m == SDIM) x = wqf;
            dst[m * BK + (k ^ ((m & 7) << 3))] = (__bf16)x;
        }
    };

    auto compute = [&](int ch, int b) {
        const float* zp = z + (size_t)(r0 + col) * LATENT + ch * BK + kh * 64 + g4 * 8;
        f32x4 za0 = *(const f32x4*)(zp);
        f32x4 za1 = *(const f32x4*)(zp + 4);
        f32x4 zb0 = *(const f32x4*)(zp + 32);
        f32x4 zb1 = *(const f32x4*)(zp + 36);
        const __bf16* src = Ab + b * 80 * BK;
        const int kl0 = kh * 64 + g4 * 8;
        bf16x8 bv;
        bv[0] = (__bf16)za0[0]; bv[1] = (__bf16)za0[1];
        bv[2] = (__bf16)za0[2]; bv[3] = (__bf16)za0[3];
        bv[4] = (__bf16)za1[0]; bv[5] = (__bf16)za1[1];
        bv[6] = (__bf16)za1[2]; bv[7] = (__bf16)za1[3];
        #pragma unroll
        for (int mt = 0; mt < MT; ++mt) {
            const int m = mt * 16 + col;
            bf16x8 av = *(const bf16x8*)(src + m * BK + (kl0 ^ ((m & 7) << 3)));
            acc[mt] = __builtin_amdgcn_mfma_f32_16x16x32_bf16(av, bv, acc[mt], 0, 0, 0);
        }
        const int kl1 = kl0 + 32;
        bv[0] = (__bf16)zb0[0]; bv[1] = (__bf16)zb0[1];
        bv[2] = (__bf16)zb0[2]; bv[3] = (__bf16)zb0[3];
        bv[4] = (__bf16)zb1[0]; bv[5] = (__bf16)zb1[1];
        bv[6] = (__bf16)zb1[2]; bv[7] = (__bf16)zb1[3];
        #pragma unroll
        for (int mt = 0; mt < MT; ++mt) {
            const int m = mt * 16 + col;
            bf16x8 av = *(const bf16x8*)(src + m * BK + (kl1 ^ ((m & 7) << 3)));
            acc[mt] = __builtin_amdgcn_mfma_f32_16x16x32_bf16(av, bv, acc[mt], 0, 0, 0);
        }
    };

    build(0, 0);
    __syncthreads();
    #pragma unroll 2
    for (int ch = 0; ch < NCH; ++ch) {
        const int b = ch & 1;
        if (ch + 1 < NCH) build(ch + 1, b ^ 1);
        compute(ch, b);
        __syncthreads();
    }

    if (kh == 1) {
        #pragma unroll
        for (int mt = 0; mt < MT; ++mt)
            #pragma unroll
            for (int r = 0; r < 4; ++r) red[rg][mt][r][lane] = acc[mt][r];
    }
    __syncthreads();
    if (kh == 0) {
        #pragma unroll
        for (int mt = 0; mt < MT; ++mt)
            #pragma unroll
            for (int r = 0; r < 4; ++r) acc[mt][r] += red[rg][mt][r][lane];
        if (g4 == 0) srow[rg][col] = acc[4][0];
    }
    __syncthreads();

    if (kh == 0) {
        const float s = srow[rg][col] + cvals[64];
        const int bidx = r0 + col;
        #pragma unroll
        for (int mt = 0; mt < 4; ++mt) {
            f32x4 cv = *(const f32x4*)(cvals + mt * 16 + g4 * 4);
            f32x4 bf = *(const f32x4*)(bfin + mt * 16 + g4 * 4);
            f32x4 ov;
            #pragma unroll
            for (int r = 0; r < 4; ++r) ov[r] = s * (acc[mt][r] + cv[r]) + bf[r];
            *(f32x4*)(out + (size_t)bidx * SDIM + mt * 16 + g4 * 4) = ov;
        }
    }
}

extern "C" void kernel_launch(void* const* d_in, const int* in_sizes, int n_in,
                              void* d_out, int out_size, void* d_ws, size_t ws_size,
                              hipStream_t stream)
{
    const float* z    = (const float*)d_in[0];
    const float* wq   = (const float*)d_in[1];
    const float* bq   = (const float*)d_in[2];
    const float* wk   = (const float*)d_in[3];
    const float* bk   = (const float*)d_in[4];
    const float* Wf   = (const float*)d_in[5];
    const float* bfin = (const float*)d_in[6];
    const int*   midx = (const int*)d_in[7];
    const int F = in_sizes[1];
    float* out = (float*)d_out;

    if (ws_size >= (size_t)WS_NEED) {
        char* ws = (char*)d_ws;
        float*  c     = (float*)ws;                  // 65 floats
        bf16x8* afrag = (bf16x8*)(ws + 4096);        // 640 KB
        prep_all <<<161, 256, 0, stream>>>(wq, wk, Wf, midx, bq, bk, F, afrag, c);
        gemm_pipe<<<512, 512, 0, stream>>>(z, afrag, c, bfin, out);
    } else {
        fused_kernel<<<256, 512, 0, stream>>>(z, wq, bq, wk, bk, Wf, bfin, midx, F, out);
    }
}

// Round 13
// 83.439 us; speedup vs baseline: 2.5239x; 2.5239x over previous
//
#include <hip/hip_runtime.h>
#include <hip/hip_bf16.h>

#define LATENT 4096
#define SDIM   64
#define MT     5              // 5 m-tiles of 16 = 80 rows (64 outputs + s_row + pad)
#define CHUNK  128            // floats of K per staged chunk (= 4 k-steps)
#define NCHK   (LATENT / CHUNK)   // 32
#define NBUF   4
#define ROWS   32             // batch rows per block
#define WS_NEED (4096 + 40960 * 16)

typedef __bf16 bf16x8 __attribute__((ext_vector_type(8)));
typedef float  f32x4  __attribute__((ext_vector_type(4)));

#define GLOBAL_AS __attribute__((address_space(1)))
#define LDS_AS    __attribute__((address_space(3)))

__device__ __forceinline__ void load_lds16(const float* g, float* l) {
    __builtin_amdgcn_global_load_lds((const GLOBAL_AS void*)g, (LDS_AS void*)l, 16, 0, 0);
}

#define WAITB(N) do { asm volatile("s_waitcnt vmcnt(" #N ")" ::: "memory"); \
                      __builtin_amdgcn_s_barrier(); } while (0)

// ======================= precompute path (needs d_ws) =======================
// Separate prep kernels (r10 form — the merged prep_all's single-block c[]
// builder was latency-serialized and cost ~130us; this version is ~3us).

// c[o] = sum_f bk[f]*W[o,f] (o<64); c[64] = sum_f bq[f]. 65 blocks x 64 lanes.
__global__ void prep_c(const float* __restrict__ bq, const float* __restrict__ bk,
                       const float* __restrict__ Wf, int F, float* __restrict__ c) {
    int o = blockIdx.x, lane = threadIdx.x;
    float p = 0.f;
    if (o < SDIM) { for (int f = lane; f < F; f += 64) p += bk[f] * Wf[o * F + f]; }
    else          { for (int f = lane; f < F; f += 64) p += bq[f]; }
    for (int off = 32; off; off >>= 1) p += __shfl_down(p, off);
    if (lane == 0) c[o] = p;
}

// bf16 A-fragments, fragment-linear: idx = ((ks*5+mt)*64+lane)
__global__ __launch_bounds__(256) void prep_afrag(
    const float* __restrict__ wq, const float* __restrict__ wk,
    const float* __restrict__ Wf, const int* __restrict__ midx,
    int F, bf16x8* __restrict__ afrag)
{
    __shared__ int inv[LATENT];
    const int t = threadIdx.x;
    #pragma unroll
    for (int d = t; d < LATENT; d += 256) inv[d] = -1;
    __syncthreads();
    for (int f = t; f < F; f += 256) inv[midx[f]] = f;
    __syncthreads();

    const int g = blockIdx.x * 256 + t;          // 0 .. 40959
    const int lane = g & 63;
    const int mt = (g >> 6) % 5;
    const int ks = g / 320;                      // 0 .. 127
    const int m = mt * 16 + (lane & 15);
    const int kbase = ks * 32 + (lane >> 4) * 8;
    bf16x8 v;
    #pragma unroll
    for (int j = 0; j < 8; ++j) {
        int f = inv[kbase + j];
        float x = 0.f;
        if (f >= 0) {
            if (m < SDIM) x = wk[f] * Wf[m * F + f];
            else if (m == SDIM) x = wq[f];
        }
        v[j] = (__bf16)x;
    }
    afrag[g] = v;
}

struct AF { bf16x8 a0, a1, a2, a3, a4; };

// main: D[80 x 16384] = A[80 x 4096] * z^T, counted-vmcnt deep ring pipeline.
// 512 blocks x 512 thr (8 waves): wave = (kq 0..3) x (nh 0..1).
// 2 blocks/CU (64KB LDS) x 8 waves = 16 waves/CU = 4/SIMD.
__global__ __launch_bounds__(512, 3) void gemm_pipe(
    const float* __restrict__ z, const bf16x8* __restrict__ afrag,
    const float* __restrict__ c, const float* __restrict__ bfin,
    float* __restrict__ out)
{
    __shared__ __align__(16) float zbuf[NBUF][ROWS][CHUNK];   // 64 KB
    float (*red)[2][MT][4][64] = (float (*)[2][MT][4][64])zbuf;  // [grp][nh][mt][r][lane]

    const int tid  = threadIdx.x;
    const int lane = tid & 63;
    const int wid  = tid >> 6;     // 0..7
    const int kq   = wid & 3;      // k-step within chunk
    const int nh   = wid >> 2;     // n-half (rows 0-15 / 16-31)
    const int col  = lane & 15;
    const int g4   = lane >> 4;
    const int r0   = blockIdx.x * ROWS;
    const int ra   = 4 * wid;      // this wave stages LDS rows ra..ra+3

    // global sources for the 2 staging instrs; column pre-swizzled so that
    // LDS float pos p (linear dest) holds z col (p ^ ((ldsrow&7)<<2)).
    const int half  = lane >> 5;          // 0..1 (row within a 2-row pair)
    const int cbase = (lane & 31) * 4;    // 16B slot within row
    const int lr0 = ra + half, lr1 = ra + 2 + half;
    const float* zsrc0 = z + (size_t)(r0 + lr0) * LATENT + (cbase ^ ((lr0 & 7) << 2));
    const float* zsrc1 = z + (size_t)(r0 + lr1) * LATENT + (cbase ^ ((lr1 & 7) << 2));

    f32x4 acc[MT] = {};

    auto stage = [&](int cN) {   // 2 VMEM ops (4 LDS rows)
        float* d = &zbuf[cN & 3][ra][0];
        load_lds16(zsrc0 + cN * CHUNK, d);
        load_lds16(zsrc1 + cN * CHUNK, d + 256);
    };
    auto loadA = [&](int cN, AF& Fr) {   // 5 VMEM ops
        const bf16x8* p = afrag + (size_t)((cN * 4 + kq) * MT) * 64 + lane;
        Fr.a0 = p[0]; Fr.a1 = p[64]; Fr.a2 = p[128]; Fr.a3 = p[192]; Fr.a4 = p[256];
    };
    auto consume = [&](int cN, const AF& Fr) {
        const int q = cN & 3;
        const int base = kq * 32 + g4 * 8;         // multiple of 8
        const int b0 = base ^ ((col & 7) << 2);    // 16B-aligned
        const float* pr = &zbuf[q][nh * 16 + col][0];
        f32x4 a = *(const f32x4*)(pr + b0);
        f32x4 b = *(const f32x4*)(pr + (b0 ^ 4));
        bf16x8 bv;
        bv[0] = (__bf16)a[0]; bv[1] = (__bf16)a[1];
        bv[2] = (__bf16)a[2]; bv[3] = (__bf16)a[3];
        bv[4] = (__bf16)b[0]; bv[5] = (__bf16)b[1];
        bv[6] = (__bf16)b[2]; bv[7] = (__bf16)b[3];
        acc[0] = __builtin_amdgcn_mfma_f32_16x16x32_bf16(Fr.a0, bv, acc[0], 0, 0, 0);
        acc[1] = __builtin_amdgcn_mfma_f32_16x16x32_bf16(Fr.a1, bv, acc[1], 0, 0, 0);
        acc[2] = __builtin_amdgcn_mfma_f32_16x16x32_bf16(Fr.a2, bv, acc[2], 0, 0, 0);
        acc[3] = __builtin_amdgcn_mfma_f32_16x16x32_bf16(Fr.a3, bv, acc[3], 0, 0, 0);
        acc[4] = __builtin_amdgcn_mfma_f32_16x16x32_bf16(Fr.a4, bv, acc[4], 0, 0, 0);
    };

    AF f_a, f_b, f_c;
    // prologue: sets 0,1 in flight (7 ops each -> 14 outstanding)
    loadA(0, f_a); stage(0);
    loadA(1, f_b); stage(1);

    // steady state: issue set h+2, WAIT vmcnt(14) (leaves {h+1,h+2}), consume h.
    for (int hb = 0; hb < NCHK - 2; hb += 3) {
        loadA(hb + 2, f_c); stage(hb + 2);
        WAITB(14); consume(hb,     f_a);
        loadA(hb + 3, f_a); stage(hb + 3);
        WAITB(14); consume(hb + 1, f_b);
        loadA(hb + 4, f_b); stage(hb + 4);
        WAITB(14); consume(hb + 2, f_c);
    }
    // tail: outstanding = sets {30,31}
    WAITB(7); consume(30, f_a);
    WAITB(0); consume(31, f_b);

    // ---- reduce the 4 kq partials per n-half (zbuf reused; barrier protects) ----
    __syncthreads();
    if (kq >= 2) {
        #pragma unroll
        for (int mt = 0; mt < MT; ++mt)
            #pragma unroll
            for (int r = 0; r < 4; ++r) red[kq - 2][nh][mt][r][lane] = acc[mt][r];
    }
    __syncthreads();
    if (kq < 2) {
        #pragma unroll
        for (int mt = 0; mt < MT; ++mt)
            #pragma unroll
            for (int r = 0; r < 4; ++r) acc[mt][r] += red[kq][nh][mt][r][lane];
    }
    __syncthreads();
    if (kq == 1) {
        #pragma unroll
        for (int mt = 0; mt < MT; ++mt)
            #pragma unroll
            for (int r = 0; r < 4; ++r) red[2][nh][mt][r][lane] = acc[mt][r];
    }
    __syncthreads();
    if (kq == 0) {
        #pragma unroll
        for (int mt = 0; mt < MT; ++mt)
            #pragma unroll
            for (int r = 0; r < 4; ++r) acc[mt][r] += red[2][nh][mt][r][lane];

        // s-row (m=64) lives in acc[4][0] of lanes 0-15; broadcast via shuffle
        const float s = __shfl(acc[4][0], col) + c[SDIM];
        const int b = r0 + nh * 16 + col;
        #pragma unroll
        for (int mt = 0; mt < 4; ++mt) {
            f32x4 cv = *(const f32x4*)(c    + mt * 16 + g4 * 4);
            f32x4 bf = *(const f32x4*)(bfin + mt * 16 + g4 * 4);
            f32x4 ov;
            #pragma unroll
            for (int r = 0; r < 4; ++r) ov[r] = s * (acc[mt][r] + cv[r]) + bf[r];
            *(f32x4*)(out + (size_t)b * SDIM + mt * 16 + g4 * 4) = ov;
        }
    }
}

// ================== fused fallback (round-2 kernel, verbatim) ==================
#define BK     128
#define NCH    (LATENT / BK)

__global__ __launch_bounds__(512, 2) void fused_kernel(
    const float* __restrict__ z,
    const float* __restrict__ wq, const float* __restrict__ bq,
    const float* __restrict__ wk, const float* __restrict__ bk,
    const float* __restrict__ Wf, const float* __restrict__ bfin,
    const int* __restrict__ midx, int F,
    float* __restrict__ out)
{
    __shared__ __align__(16) unsigned char ubuf[2 * 80 * BK * 2];
    __shared__ int   inv[LATENT];
    __shared__ float cvals[68];
    __shared__ float srow[4][16];

    __bf16* Ab = (__bf16*)ubuf;
    float (*red)[MT][4][64] = (float (*)[MT][4][64])ubuf;

    const int tid  = threadIdx.x;
    const int lane = tid & 63;
    const int w    = tid >> 6;
    const int rg   = w & 3;
    const int kh   = w >> 2;
    const int r0   = blockIdx.x * 64 + rg * 16;
    const int col  = lane & 15;
    const int g4   = lane >> 4;

    for (int d = tid; d < LATENT; d += 512) inv[d] = -1;
    __syncthreads();
    for (int f = tid; f < F; f += 512) inv[midx[f]] = f;
    {
        const int o = tid >> 3, fo = tid & 7;
        float p = 0.f;
        for (int f = fo; f < F; f += 8) p += bk[f] * Wf[o * F + f];
        p += __shfl_xor(p, 1); p += __shfl_xor(p, 2); p += __shfl_xor(p, 4);
        if (fo == 0) cvals[o] = p;
    }
    if (w == 0) {
        float q = 0.f;
        for (int f = lane; f < F; f += 64) q += bq[f];
        #pragma unroll
        for (int off = 32; off; off >>= 1) q += __shfl_down(q, off);
        if (lane == 0) cvals[64] = q;
    }
    __syncthreads();

    f32x4 acc[MT] = {};

    auto build = [&](int ch, int b) {
        const int k  = tid & 127;
        const int mb = tid >> 7;
        const int f  = inv[ch * BK + k];
        const float wkf = (f >= 0) ? wk[f] : 0.f;
        const float wqf = (f >= 0) ? wq[f] : 0.f;
        __bf16* dst = Ab + b * 80 * BK;
        #pragma unroll
        for (int i = 0; i < 20; ++i) {
            const int m = mb + 4 * i;
            float x = 0.f;
            if (m < SDIM) { if (f >= 0) x = wkf * Wf[m * F + f]; }
            else if (m == SDIM) x = wqf;
            dst[m * BK + (k ^ ((m & 7) << 3))] = (__bf16)x;
        }
    };

    auto compute = [&](int ch, int b) {
        const float* zp = z + (size_t)(r0 + col) * LATENT + ch * BK + kh * 64 + g4 * 8;
        f32x4 za0 = *(const f32x4*)(zp);
        f32x4 za1 = *(const f32x4*)(zp + 4);
        f32x4 zb0 = *(const f32x4*)(zp + 32);
        f32x4 zb1 = *(const f32x4*)(zp + 36);
        const __bf16* src = Ab + b * 80 * BK;
        const int kl0 = kh * 64 + g4 * 8;
        bf16x8 bv;
        bv[0] = (__bf16)za0[0]; bv[1] = (__bf16)za0[1];
        bv[2] = (__bf16)za0[2]; bv[3] = (__bf16)za0[3];
        bv[4] = (__bf16)za1[0]; bv[5] = (__bf16)za1[1];
        bv[6] = (__bf16)za1[2]; bv[7] = (__bf16)za1[3];
        #pragma unroll
        for (int mt = 0; mt < MT; ++mt) {
            const int m = mt * 16 + col;
            bf16x8 av = *(const bf16x8*)(src + m * BK + (kl0 ^ ((m & 7) << 3)));
            acc[mt] = __builtin_amdgcn_mfma_f32_16x16x32_bf16(av, bv, acc[mt], 0, 0, 0);
        }
        const int kl1 = kl0 + 32;
        bv[0] = (__bf16)zb0[0]; bv[1] = (__bf16)zb0[1];
        bv[2] = (__bf16)zb0[2]; bv[3] = (__bf16)zb0[3];
        bv[4] = (__bf16)zb1[0]; bv[5] = (__bf16)zb1[1];
        bv[6] = (__bf16)zb1[2]; bv[7] = (__bf16)zb1[3];
        #pragma unroll
        for (int mt = 0; mt < MT; ++mt) {
            const int m = mt * 16 + col;
            bf16x8 av = *(const bf16x8*)(src + m * BK + (kl1 ^ ((m & 7) << 3)));
            acc[mt] = __builtin_amdgcn_mfma_f32_16x16x32_bf16(av, bv, acc[mt], 0, 0, 0);
        }
    };

    build(0, 0);
    __syncthreads();
    #pragma unroll 2
    for (int ch = 0; ch < NCH; ++ch) {
        const int b = ch & 1;
        if (ch + 1 < NCH) build(ch + 1, b ^ 1);
        compute(ch, b);
        __syncthreads();
    }

    if (kh == 1) {
        #pragma unroll
        for (int mt = 0; mt < MT; ++mt)
            #pragma unroll
            for (int r = 0; r < 4; ++r) red[rg][mt][r][lane] = acc[mt][r];
    }
    __syncthreads();
    if (kh == 0) {
        #pragma unroll
        for (int mt = 0; mt < MT; ++mt)
            #pragma unroll
            for (int r = 0; r < 4; ++r) acc[mt][r] += red[rg][mt][r][lane];
        if (g4 == 0) srow[rg][col] = acc[4][0];
    }
    __syncthreads();

    if (kh == 0) {
        const float s = srow[rg][col] + cvals[64];
        const int bidx = r0 + col;
        #pragma unroll
        for (int mt = 0; mt < 4; ++mt) {
            f32x4 cv = *(const f32x4*)(cvals + mt * 16 + g4 * 4);
            f32x4 bf = *(const f32x4*)(bfin + mt * 16 + g4 * 4);
            f32x4 ov;
            #pragma unroll
            for (int r = 0; r < 4; ++r) ov[r] = s * (acc[mt][r] + cv[r]) + bf[r];
            *(f32x4*)(out + (size_t)bidx * SDIM + mt * 16 + g4 * 4) = ov;
        }
    }
}

extern "C" void kernel_launch(void* const* d_in, const int* in_sizes, int n_in,
                              void* d_out, int out_size, void* d_ws, size_t ws_size,
                              hipStream_t stream)
{
    const float* z    = (const float*)d_in[0];
    const float* wq   = (const float*)d_in[1];
    const float* bq   = (const float*)d_in[2];
    const float* wk   = (const float*)d_in[3];
    const float* bk   = (const float*)d_in[4];
    const float* Wf   = (const float*)d_in[5];
    const float* bfin = (const float*)d_in[6];
    const int*   midx = (const int*)d_in[7];
    const int F = in_sizes[1];
    float* out = (float*)d_out;

    if (ws_size >= (size_t)WS_NEED) {
        char* ws = (char*)d_ws;
        float*  c     = (float*)ws;                  // 65 floats
        bf16x8* afrag = (bf16x8*)(ws + 4096);        // 640 KB
        prep_c    <<<65,  64,  0, stream>>>(bq, bk, Wf, F, c);
        prep_afrag<<<160, 256, 0, stream>>>(wq, wk, Wf, midx, F, afrag);
        gemm_pipe <<<512, 512, 0, stream>>>(z, afrag, c, bfin, out);
    } else {
        fused_kernel<<<256, 512, 0, stream>>>(z, wq, bq, wk, bk, Wf, bfin, midx, F, out);
    }
}